// Round 12
// baseline (88.522 us; speedup 1.0000x reference)
//
#include <hip/hip_runtime.h>

// LocallyConnected2d: out[b,o,p,q] = sum_{i,kh,kw} x[b,i,2p+kh,2q+kw] * w[o,i,p,q,kh*3+kw]
// x: (8,32,64,64) f32, w: (1,32,32,31,31,9) f32, out: (8,32,31,31) f32
//
// R11 was LDS-instruction bound (~1M wave ds_reads: 1 o/thread gave 33 reads
// per 36 FMA). Now: 256 thr = 8 ol x 2 bh x 16 dq; thread computes 4 o x 4 b
// x 2 i -> 288 FMA per 96 ds_reads. x packed as [row][q][4-col window] so each
// (kh,bi) is ONE ds_read_b128 (GLD4 per-lane global addr does the repack).
// w in [o][145] segs (odd stride -> b32 reads ~conflict-free). All staging
// up-front (50 GLD4/thread, 600 outstanding/CU), ONE barrier, pure-LDS compute.
// LDS 50 KB -> 3 blocks/CU. Grid (p31, qg2, ih16) = 992; 2 i per block.
// Partials -> d_ws (16 groups) + reduce kernel. No atomics (R6: 106MB RMW).

#define NPART 246016              // 8b * 961pq * 32o floats per i-group
#define NIG 16
#define WS_NEED ((size_t)NIG * NPART * 4)

#define GLD4(gp, lp)                                                 \
    __builtin_amdgcn_global_load_lds(                                \
        (const __attribute__((address_space(1))) void*)(gp),         \
        (__attribute__((address_space(3))) void*)(lp), 4, 0, 0)

template <bool USE_WS>
__global__ __launch_bounds__(256, 3) void lc2d_kernel(const float* __restrict__ x,
                                                      const float* __restrict__ wgt,
                                                      float* __restrict__ outOrPart) {
    __shared__ float xs[3072];        // [r48 = (b*2+ii)*3+kh][dq16][4 cols] = 12 KB
    __shared__ float wl[2][4864];     // [ii][o*145+off] 4640 used + clamp slack = 38 KB

    const int t  = threadIdx.x;
    const int ol = t & 7;             // o = ol + 8*oj, oj 0..3
    const int bh = (t >> 3) & 1;      // b in [bh*4, bh*4+4)
    const int dq = t >> 4;            // 0..15
    const int bid = blockIdx.x;
    const int p  = bid >> 5;          // 0..30
    const int qg = (bid >> 4) & 1;
    const int ih = bid & 15;          // i-pair index
    const int i0 = ih * 2;
    const int q0 = qg << 4;
    const int q  = q0 + dq;           // q=31 computes dup (clamped), never stored
    const int waveBase = t & ~63;

    // ---- stage x windowed: xs[(r*16+dq')*4+c] = x[b][i0+ii][2p+kh][min(2*(q0+dq')+c,63)]
    //      r = (b*2+ii)*3+kh. 12 GLD4, exact (3072 = 12*256).
#pragma unroll
    for (int j = 0; j < 12; ++j) {
        const int f   = j * 256 + t;
        const int c   = f & 3;
        const int dqp = (f >> 2) & 15;
        const int r   = f >> 6;       // 0..47
        const int b   = r / 6;
        const int r6  = r - b * 6;
        const int ii  = r6 / 3;
        const int kh  = r6 - ii * 3;
        int gcol = 2 * (q0 + dqp) + c;
        if (gcol > 63) gcol = 63;     // only q=31 dup-lane entries, never stored
        const float* gp = x + (size_t)b * 131072 + (size_t)(i0 + ii) * 4096
                            + (size_t)(2 * p + kh) * 64 + gcol;
        GLD4(gp, &xs[j * 256 + waveBase]);
    }

    // ---- stage w: wl[ii][os*145+off] <- wgt[os*276768 + pqb + min(off,lim) + (i0+ii)*8649]
    const int lim = (qg == 0) ? 143 : 134;  // valid words per o-seg - 1 (pads dup, never read)
    const int pqb = p * 279 + q0 * 9;
#pragma unroll
    for (int ii = 0; ii < 2; ++ii) {
        const size_t iw = (size_t)(i0 + ii) * 8649;
#pragma unroll
        for (int j = 0; j < 19; ++j) {
            int f = j * 256 + t; f = (f < 4639) ? f : 4639;  // clamp GLOBAL only; LDS dest linear
            const int os  = f / 145;
            const int off = f - os * 145;
            const int go  = (off < lim) ? off : lim;
            GLD4(wgt + (size_t)os * 276768 + pqb + go + iw,
                 &wl[ii][j * 256 + waveBase]);
        }
    }

    float acc[4][4];                  // [oj][bi]
#pragma unroll
    for (int oj = 0; oj < 4; ++oj)
#pragma unroll
        for (int bi = 0; bi < 4; ++bi) acc[oj][bi] = 0.f;

    __syncthreads();                  // ONE barrier: drains all 50 staged issues

#pragma unroll
    for (int ii = 0; ii < 2; ++ii) {
        // x fragments: one b128 per (kh,bi); broadcast across ol lanes
        float4 xv[3][4];
#pragma unroll
        for (int kh = 0; kh < 3; ++kh)
#pragma unroll
            for (int bi = 0; bi < 4; ++bi) {
                const int r = ((bh * 4 + bi) * 2 + ii) * 3 + kh;
                xv[kh][bi] = *reinterpret_cast<const float4*>(&xs[(r * 16 + dq) * 4]);
            }

#pragma unroll
        for (int oj = 0; oj < 4; ++oj) {
            const int wbase = (ol + 8 * oj) * 145 + dq * 9;  // odd stride: ~conflict-free
            float wv[9];
#pragma unroll
            for (int k = 0; k < 9; ++k) wv[k] = wl[ii][wbase + k];
#pragma unroll
            for (int kh = 0; kh < 3; ++kh)
#pragma unroll
                for (int bi = 0; bi < 4; ++bi)
                    acc[oj][bi] += wv[kh * 3 + 0] * xv[kh][bi].x
                                 + wv[kh * 3 + 1] * xv[kh][bi].y
                                 + wv[kh * 3 + 2] * xv[kh][bi].z;
        }
    }

    if (q <= 30) {
        const int pq = p * 31 + q;
        if (USE_WS) {
            // part[((ih*8+b)*961 + pq)*32 + o]: wave's 4 oj-instrs fill full
            // 32-word o-runs per (b,pq) -> L2 merges to full lines
#pragma unroll
            for (int oj = 0; oj < 4; ++oj)
#pragma unroll
                for (int bi = 0; bi < 4; ++bi)
                    outOrPart[((size_t)(ih * 8 + bh * 4 + bi) * 961 + pq) * 32 + ol + 8 * oj]
                        = acc[oj][bi];
        } else {
#pragma unroll
            for (int oj = 0; oj < 4; ++oj)
#pragma unroll
                for (int bi = 0; bi < 4; ++bi)
                    atomicAdd(&outOrPart[(((size_t)(bh * 4 + bi) * 32 + ol + 8 * oj) * 31 + p) * 31 + q],
                              acc[oj][bi]);
        }
    }
}

__global__ __launch_bounds__(256) void lc2d_reduce(const float* __restrict__ part,
                                                   float* __restrict__ out) {
    const int u = blockIdx.x * 256 + threadIdx.x;   // grid exactly covers 246016
    float s = 0.f;
#pragma unroll
    for (int ig = 0; ig < NIG; ++ig) s += part[(size_t)ig * NPART + u];  // 16 coalesced streams
    const int o = u & 31;
    const int r = u >> 5;
    const int b = r / 961;
    const int pq = r - b * 961;
    out[(size_t)(b * 32 + o) * 961 + pq] = s;
}

extern "C" void kernel_launch(void* const* d_in, const int* in_sizes, int n_in,
                              void* d_out, int out_size, void* d_ws, size_t ws_size,
                              hipStream_t stream) {
    const float* x = (const float*)d_in[0];
    const float* w = (const float*)d_in[1];
    float* out = (float*)d_out;

    if (ws_size >= WS_NEED) {
        float* part = (float*)d_ws;
        lc2d_kernel<true><<<dim3(31 * 2 * 16), dim3(256), 0, stream>>>(x, w, part);
        lc2d_reduce<<<dim3(NPART / 256), dim3(256), 0, stream>>>(part, out);
    } else {
        hipMemsetAsync(out, 0, (size_t)out_size * sizeof(float), stream);
        lc2d_kernel<false><<<dim3(31 * 2 * 16), dim3(256), 0, stream>>>(x, w, out);
    }
}